// Round 17
// baseline (391.393 us; speedup 1.0000x reference)
//
#include <hip/hip_runtime.h>
#include <math.h>
#include <string.h>

typedef unsigned short ushort_t;
typedef __attribute__((ext_vector_type(8))) short bhalf8;
typedef __attribute__((ext_vector_type(4))) float floatx4;

// Problem constants
#define NN    8
#define CC_   96
#define HH    56
#define WW    56
#define HWHW  (HH*WW)            // 3136
#define NPIX  (NN*HWHW)          // 25088
#define NELEM (NN*CC_*HWHW)      // 2408448
#define GROUPS 4
#define IG    24                 // channels per group
#define NITER 25
#define EPSV  1e-12f
#define TS    40                 // LDS ch-slot stride (ushorts) = 80 B

// bf16 helpers (RNE)
__device__ __forceinline__ unsigned bf2pack(float a, float b) {
    unsigned ua = __float_as_uint(a), ub = __float_as_uint(b);
    ua += 0x7fffu + ((ua >> 16) & 1u);
    ub += 0x7fffu + ((ub >> 16) & 1u);
    return (ua >> 16) | (ub & 0xffff0000u);
}
__device__ __forceinline__ ushort_t bf1pack(float a) {
    unsigned ua = __float_as_uint(a);
    ua += 0x7fffu + ((ua >> 16) & 1u);
    return (ushort_t)(ua >> 16);
}
__device__ __forceinline__ float bflo(unsigned u) { return __uint_as_float(u << 16); }
__device__ __forceinline__ float bfhi(unsigned u) { return __uint_as_float(u & 0xffff0000u); }

// fast reciprocal: v_rcp_f32 (~1 ulp), error far below bf16 pack rounding
__device__ __forceinline__ float rcpf(float x) {
    float r;
    asm("v_rcp_f32 %0, %1" : "=v"(r) : "v"(x));
    return r;
}

// Linear LDS addressing (R10): TS=40 ushorts = 20 dwords is bank-optimal for
// ds_read_b128 (8 consecutive lanes -> 8 disjoint 4-bank groups; nn/nn+8
// alias exactly = free 2-way).
__device__ __forceinline__ int swz(int slot, int u) {
    return slot*TS + u;
}

// ---------------------------------------------------------------------------
// Fused prep: blocks 0-3    = wnorm+wpack (per group g)
//             blocks 4-39   = mlppack (4 frag-sets per block)
//             blocks 40-235 = ln1 (128 px per block, 2 threads/px)
// Xp packed as uint2 channel-quads: Xp2[(ng*6+pr2)*HWHW + hw].
__global__ __launch_bounds__(256) void prep_kernel(
        const float* __restrict__ w_in,
        ushort_t* __restrict__ WfP, ushort_t* __restrict__ WtP,
        const float* __restrict__ w1, const float* __restrict__ w2,
        ushort_t* __restrict__ w1P, ushort_t* __restrict__ w2P,
        const float* __restrict__ x, const float* __restrict__ lw1,
        const float* __restrict__ lb1, unsigned* __restrict__ Xp) {
    __shared__ float wn[24*216];         // 20736 B (reused by ln1 reductions)
    __shared__ float rsum[24];
    int b = blockIdx.x;
    int tid = threadIdx.x;

    if (b < 4) {
        int g = b;
        if (tid < 24) {
            const float* wr = w_in + (size_t)(g*24 + tid)*216;
            float s = 0.f;
            for (int j = 0; j < 216; ++j) s += fabsf(wr[j]);
            rsum[tid] = s;
        }
        __syncthreads();
        for (int i = tid; i < 24*216; i += 256) {
            int row = i / 216;
            wn[i] = fabsf(w_in[(size_t)g*24*216 + i]) * rcpf(rsum[row] + EPSV);
        }
        __syncthreads();
        int lg = tid >> 6;               // 0..3
        int lane = tid & 63;
        int quad = lane >> 4, nn15 = lane & 15;
        #pragma unroll 1
        for (int i = 0; i < 9; ++i) {
            int fr  = lg + 4*i;          // 0..35
            int sel = fr / 18;
            int rem = fr % 18;
            int ot  = rem & 1;
            int tap = rem >> 1;
            int m = ot*16 + nn15;
            ushort_t v[8];
            #pragma unroll
            for (int j = 0; j < 8; ++j) {
                int kc = quad*8 + j;
                float val = 0.f;
                if (m < IG && kc < IG) {
                    if (sel == 0) val = wn[m*216 + kc*9 + tap];
                    else          val = wn[kc*216 + m*9 + (8 - tap)];
                }
                v[j] = bf1pack(val);
            }
            ushort_t* dst = (sel ? WtP : WfP) + ((size_t)((g*9 + tap)*2 + ot)*64 + lane)*8;
            *(uint4*)dst = *(uint4*)v;
        }
    } else if (b < 40) {
        int f = (b - 4)*4 + (tid >> 6);  // 0..143
        int lane = tid & 63;
        int quad = lane >> 4, nn15 = lane & 15;
        ushort_t v[8];
        if (f < 72) {
            int nt = f / 3, ks = f % 3;
            #pragma unroll
            for (int j = 0; j < 8; ++j)
                v[j] = bf1pack(w1[(size_t)(ks*32 + quad*8 + j)*384 + nt*16 + nn15]);
            *(uint4*)(w1P + ((size_t)f*64 + lane)*8) = *(uint4*)v;
        } else {
            int f2 = f - 72;
            int mt = f2 / 12, ks = f2 % 12;
            #pragma unroll
            for (int j = 0; j < 8; ++j)
                v[j] = bf1pack(w2[(size_t)(ks*32 + quad*8 + j)*96 + mt*16 + nn15]);
            *(uint4*)(w2P + ((size_t)f2*64 + lane)*8) = *(uint4*)v;
        }
    } else {
        // ---- LN1: 128 px/block, 2 threads per px (channel halves, reg cache)
        float* ps  = wn;                 // 256
        float* pss = wn + 256;           // 256
        float* psr = wn + 512;           // 256
        int pb = b - 40;                 // 0..195
        int px = tid & 127;
        int ch0 = (tid >> 7) * 48;       // 0 or 48
        int p = pb*128 + px;             // < NPIX exactly (196*128)
        int n = p / HWHW, hw = p % HWHW;
        const float* xp = x + (size_t)n*CC_*HWHW + (size_t)ch0*HWHW + hw;
        float v[48];
        float s = 0.f, ss = 0.f;
        #pragma unroll
        for (int j = 0; j < 48; ++j) {
            float vv = xp[(size_t)j*HWHW];
            v[j] = vv; s += vv; ss += vv*vv;
        }
        ps[tid] = s; pss[tid] = ss;
        __syncthreads();
        float S_  = ps[px]  + ps[128 + px];
        float SS_ = pss[px] + pss[128 + px];
        float u  = S_ * (1.f/CC_);
        float var = SS_ * (1.f/CC_) - u*u;
        float rs = rsqrtf(var + 1e-6f);
        float sr = 0.f;
        #pragma unroll
        for (int j = 0; j < 48; ++j) {
            float av = fmaxf((v[j]-u)*rs*lw1[ch0+j] + lb1[ch0+j], 0.f);
            v[j] = av; sr += av;
        }
        psr[tid] = sr;
        __syncthreads();
        float inv = 1.f / (psr[px] + psr[128 + px] + EPSV);
        #pragma unroll
        for (int q = 0; q < 12; ++q) {
            int c = ch0 + 4*q;
            uint2 pk;
            pk.x = bf2pack(v[4*q]*inv,   v[4*q+1]*inv);
            pk.y = bf2pack(v[4*q+2]*inv, v[4*q+3]*inv);
            int g = c / IG, pr2 = (c % IG) >> 2;
            *(uint2*)&Xp[2*(((size_t)(n*4+g)*6 + pr2)*HWHW + hw)] = pk;
        }
    }
}

// ---------------------------------------------------------------------------
// Fused NNMF iteration (MFMA), 7-row band, 512 blocks (uniform 2/CU).
// R9 vector layout (Hu/Xp uint2 quads, S float4) + R10 linear LDS addressing.
// R12 sacc epilogue; R17: phase-B ratio operands (xa/xc) hoisted BEFORE
// staging (R7-persist proven indexing) so their L2 latency overlaps the
// Hu/S prefetch + LDS staging instead of stalling phase B's start.
__global__ __launch_bounds__(512, 4) void nnmf_mfma_kernel(
        const unsigned* __restrict__ HupI, unsigned* __restrict__ HupO,
        const float* __restrict__ Scur, float* __restrict__ Snxt,
        const ushort_t* __restrict__ WtP, const ushort_t* __restrict__ WfP,
        const unsigned* __restrict__ Xp,
        int it0, unsigned huInit, float sInit) {
    __shared__ ushort_t hn[352*TS];      // HuN tile [row11*32+pos][40]  28160 B
    __shared__ ushort_t rt_[288*TS];     // R   tile [row9*32+pos][40]   23040 B
    __shared__ float sacc[392];
    int b    = blockIdx.x;               // 512
    // XCD-aware decode: xcd = b&7, 4 ng-groups x 16 tiles per XCD
    int k_   = b >> 3;                   // 0..63
    int ng   = (b & 7)*4 + (k_ >> 4);    // 0..31
    int tile = k_ & 15;                  // 0..15
    int rtb  = tile >> 1;                // 0..7 (7-row bands)
    int half = tile & 1;
    int n    = ng >> 2;
    int g    = ng & 3;
    int tid  = threadIdx.x;
    int r0   = rtb*7;
    int xb   = half*28;
    unsigned plane6 = (unsigned)(n*4 + g)*6;

    int waveId = tid >> 6, lane = tid & 63;
    int quad = lane >> 4, nn = lane & 15;
    int otB = waveId & 1;
    int mbB = otB*16 + quad*4;           // phase-B output channel base

    // rt_ K-pad zeroing first: retired long before the barrier
    if (tid < 288) *(uint4*)&rt_[swz(tid, 24)] = (uint4){0u,0u,0u,0u};

    // convT weight frags early: latency overlaps staging (ot-split: 9 frags)
    bhalf8 afrB[9];
    {
        const ushort_t* ap = WtP + ((size_t)(g*9*2 + otB)*64 + lane)*8;
        #pragma unroll
        for (int t = 0; t < 9; ++t) afrB[t] = *(const bhalf8*)(ap + (size_t)t*2*64*8);
    }

    // ---- R17: hoist phase-B ratio operands (iteration-invariant addresses)
    unsigned xaH[5], xcH[5];
    #pragma unroll
    for (int i = 0; i < 5; ++i) {
        int tk = waveId + 8*i;           // 0..39
        unsigned a = 0u, c = 0u;
        if (tk < 36) {
            int pt  = (tk >> 1) & 1;
            int row = tk >> 2;
            int x0R = pt*14;
            int gr = r0 - 1 + row, gc = xb - 1 + x0R + nn;
            if (mbB < IG && gr >= 0 && gr < HH && gc >= 0 && gc < WW) {
                unsigned off = (unsigned)(gr*WW + gc);
                uint2 xv = *(const uint2*)&Xp[2*((size_t)(plane6 + (mbB >> 2))*HWHW + off)];
                a = xv.x; c = xv.y;
            }
        }
        xaH[i] = a; xcH[i] = c;
    }

    // ---- prefetch Hu (uint2) + S (float4) for staging; 11x32 grid, 6 pr2
    uint2 raw[6];
    float sSum[6];
    #pragma unroll
    for (int kk = 0; kk < 6; ++kk) {
        int idx = tid + kk*512;          // < 2816 guarded
        uint2 rv = {0u, 0u};
        float st = 0.f;
        if (idx < 2816) {
            int pr2  = idx / 352;        // 0..7 (6 used)
            int slot = idx - pr2*352;    // 0..351
            int r = slot >> 5, q = slot & 31;
            int gr = r0 - 2 + r, gc = xb - 2 + q;
            if (!it0 && pr2 < 6 && gr >= 0 && gr < HH && gc >= 0 && gc < WW) {
                unsigned off = (unsigned)(gr*WW + gc);
                unsigned pix = (unsigned)(n*HWHW) + off;
                rv = *(const uint2*)&HupI[2*((size_t)(plane6 + pr2)*HWHW + off)];
                float4 sv = *(const float4*)&Scur[4*(size_t)pix];
                st = sv.x + sv.y + sv.z + sv.w;
            }
        }
        raw[kk] = rv;
        sSum[kk] = st;
    }

    // ---- stage HuN = Hu/S (bf16); pr2 6,7 zero the K-pad chunks
    #pragma unroll
    for (int kk = 0; kk < 6; ++kk) {
        int idx = tid + kk*512;
        if (idx < 2816) {
            int pr2  = idx / 352;
            int slot = idx - pr2*352;
            int r = slot >> 5, q = slot & 31;
            int gr = r0 - 2 + r, gc = xb - 2 + q;
            uint2 pk = {0u, 0u};
            if (pr2 < 6 && gr >= 0 && gr < HH && gc >= 0 && gc < WW) {
                if (it0) {
                    float si = rcpf(4.f*sInit + EPSV);
                    float hval = bflo(huInit) * si;
                    pk.x = bf2pack(hval, hval);
                    pk.y = pk.x;
                } else {
                    float si = rcpf(sSum[kk] + EPSV);
                    pk.x = bf2pack(bflo(raw[kk].x)*si, bfhi(raw[kk].x)*si);
                    pk.y = bf2pack(bflo(raw[kk].y)*si, bfhi(raw[kk].y)*si);
                }
            }
            *(uint2*)&hn[swz(slot, 4*pr2)] = pk;
        }
    }
    __syncthreads();

    // ---- Phase B: convT -> R band (9 rows x 30 px) in LDS; 36 tasks
    {
        #pragma unroll
        for (int i = 0; i < 5; ++i) {
            int tk = waveId + 8*i;       // 0..39, valid < 36; tk&1 == otB
            if (tk < 36) {
                int pt  = (tk >> 1) & 1;
                int row = tk >> 2;       // 0..8 (gr = r0-1+row)
                int x0R = pt*14;
                floatx4 acc = (floatx4){0.f,0.f,0.f,0.f};
                #pragma unroll
                for (int t = 0; t < 9; ++t) {
                    int ky = t / 3, kx = t % 3;
                    bhalf8 bfr = *(const bhalf8*)
                        &hn[swz((row + ky)*32 + kx + nn + x0R, quad*8)];
                    acc = __builtin_amdgcn_mfma_f32_16x16x32_bf16(afrB[t], bfr, acc, 0, 0, 0);
                }
                if (mbB < IG) {
                    int slot = row*32 + x0R + nn;
                    *(unsigned*)&rt_[swz(slot, mbB)] =
                        bf2pack(bflo(xaH[i])*rcpf(acc[0]+EPSV), bfhi(xaH[i])*rcpf(acc[1]+EPSV));
                    *(unsigned*)&rt_[swz(slot, mbB + 2)] =
                        bf2pack(bflo(xcH[i])*rcpf(acc[2]+EPSV), bfhi(xcH[i])*rcpf(acc[3]+EPSV));
                }
            }
        }
    }
    __syncthreads();

    // ---- Phase C: forward conv + mult. update; 28 tasks (7r x 2xt x 2ot)
    {
        const ushort_t* ap = WfP + ((size_t)(g*9*2 + otB)*64 + lane)*8;
        bhalf8 afr[9];
        #pragma unroll
        for (int t = 0; t < 9; ++t) afr[t] = *(const bhalf8*)(ap + (size_t)t*2*64*8);
        int mb = mbB;

        #pragma unroll
        for (int i = 0; i < 4; ++i) {
            int tc = waveId + 8*i;       // 0..31, valid < 28; tc&1 == otB
            if (tc < 28) {
                int xt = (tc >> 1) & 1;
                int w  = tc >> 2;        // out row in band, 0..6
                int px0 = xt*12;
                floatx4 acc = (floatx4){0.f,0.f,0.f,0.f};
                #pragma unroll
                for (int t = 0; t < 9; ++t) {
                    int ky = t / 3, kx = t % 3;
                    bhalf8 bfr = *(const bhalf8*)
                        &rt_[swz((w + ky)*32 + kx + nn + px0, quad*8)];
                    acc = __builtin_amdgcn_mfma_f32_16x16x32_bf16(afr[t], bfr, acc, 0, 0, 0);
                }

                int grow = r0 + w;
                int pxh = px0 + nn;      // 0..27
                float psum = 0.f;
                if (mb < IG) {
                    unsigned off = (unsigned)(grow*WW + xb + pxh);
                    uint2 hv = *(const uint2*)&hn[swz((w + 2)*32 + pxh + 2, mb)];
                    float h0 = bflo(hv.x) * acc[0];
                    float h1 = bfhi(hv.x) * acc[1];
                    float h2 = bflo(hv.y) * acc[2];
                    float h3 = bfhi(hv.y) * acc[3];
                    uint2 po; po.x = bf2pack(h0, h1); po.y = bf2pack(h2, h3);
                    *(uint2*)&HupO[2*((size_t)(plane6 + (mb >> 2))*HWHW + off)] = po;
                    psum = h0 + h1 + h2 + h3;
                }
                psum += __shfl_down(psum, 32, 64);
                psum += __shfl_down(psum, 16, 64);
                if (lane < 16) sacc[otB*196 + w*28 + pxh] = psum;
            }
        }
    }
    __syncthreads();
    if (tid < 196) {
        unsigned pix = (unsigned)(n*HWHW + (r0 + tid/28)*WW + xb + (tid % 28));
        Snxt[4*(size_t)pix + g] = sacc[tid] + sacc[196 + tid];
    }
}

// ---------------------------------------------------------------------------
// Fused residual + LN2 + MLP: 32 tokens/block, 256 thr (R10, verified).
__global__ __launch_bounds__(256) void mlpres_kernel(
        const float* __restrict__ x, const unsigned* __restrict__ Hup,
        const float* __restrict__ S4,
        const float* __restrict__ lw, const float* __restrict__ lb,
        const ushort_t* __restrict__ w1P, const float* __restrict__ b1,
        const ushort_t* __restrict__ w2P, const float* __restrict__ b2,
        float* __restrict__ out) {
    __shared__ ushort_t lh[32*392];      // 25088 B
    __shared__ unsigned xln[32*52];      // 6656 B
    __shared__ float vt[96*34];          // 13056 B
    __shared__ float redS[8*32], redSS[8*32];
    __shared__ float uArr[32], rsArr[32];
    int blk = blockIdx.x;                // 784
    int tid = threadIdx.x;
    int p0  = blk * 32;
    int n   = p0 / HWHW;                 // HWHW % 32 == 0: no straddle
    int hw0 = p0 % HWHW;

    // ---- LN phase: px = tid&31, cg = tid>>5 (12 channels each)
    {
        int px = tid & 31, cg = tid >> 5;
        int p  = p0 + px, hw = hw0 + px;
        float4 sv = *(const float4*)&S4[4*(size_t)p];
        float stot = sv.x + sv.y + sv.z + sv.w;
        float sinv = 1.f / (stot + EPSV);
        int g = cg >> 1;
        unsigned plane6 = (unsigned)(n*4 + g)*6 + (unsigned)((cg & 1)*3);
        size_t xbase = (size_t)n*CC_*HWHW + hw;
        float v[12];
        float s = 0.f, ss = 0.f;
        #pragma unroll
        for (int j2 = 0; j2 < 3; ++j2) {
            int c = cg*12 + 4*j2;
            uint2 hu = *(const uint2*)&Hup[2*((size_t)(plane6 + j2)*HWHW + hw)];
            float h[4] = { bflo(hu.x), bfhi(hu.x), bflo(hu.y), bfhi(hu.y) };
            #pragma unroll
            for (int j = 0; j < 4; ++j) {
                float vv = x[xbase + (size_t)(c+j)*HWHW] + h[j] * sinv;
                v[4*j2 + j] = vv;
                s += vv; ss += vv*vv;
            }
        }
        redS[cg*32 + px] = s; redSS[cg*32 + px] = ss;
        __syncthreads();
        if (tid < 32) {
            float S_ = 0.f, SS_ = 0.f;
            #pragma unroll
            for (int k = 0; k < 8; ++k) { S_ += redS[k*32 + tid]; SS_ += redSS[k*32 + tid]; }
            float u  = S_ * (1.f/CC_);
            float var = SS_ * (1.f/CC_) - u*u;
            uArr[tid] = u; rsArr[tid] = rsqrtf(var + 1e-5f);
        }
        __syncthreads();
        float u = uArr[px], rs = rsArr[px];
        #pragma unroll
        for (int j = 0; j < 6; ++j) {
            int c = cg*12 + 2*j;
            float a0 = (v[2*j]   - u)*rs*lw[c]   + lb[c];
            float a1 = (v[2*j+1] - u)*rs*lw[c+1] + lb[c+1];
            xln[px*52 + cg*6 + j] = bf2pack(a0, a1);
            vt[c*34 + px]     = v[2*j];
            vt[(c+1)*34 + px] = v[2*j+1];
        }
    }
    __syncthreads();

    // ---- MLP phase: 4 waves; tt = token-tile (0/1), hv_ = nt/mt half
    int wv  = tid >> 6, lane = tid & 63;
    int quad = lane >> 4, nn = lane & 15;
    int tt  = wv >> 1;
    int hv_ = wv & 1;

    bhalf8 a1[3];
    #pragma unroll
    for (int ks = 0; ks < 3; ++ks)
        a1[ks] = *(const bhalf8*)&xln[(tt*16 + nn)*52 + ks*16 + quad*4];

    #pragma unroll 1
    for (int i = 0; i < 12; ++i) {
        int nt = hv_*12 + i;
        floatx4 acc = (floatx4){0.f,0.f,0.f,0.f};
        #pragma unroll
        for (int ks = 0; ks < 3; ++ks) {
            bhalf8 bfr = *(const bhalf8*)(w1P + ((size_t)(nt*3 + ks)*64 + lane)*8);
            acc = __builtin_amdgcn_mfma_f32_16x16x32_bf16(a1[ks], bfr, acc, 0, 0, 0);
        }
        float b1v = b1[nt*16 + nn];
        #pragma unroll
        for (int r = 0; r < 4; ++r) {
            float h = acc[r] + b1v;
            h = 0.5f * h * (1.f + erff(h * 0.70710678118654752440f));
            lh[(tt*16 + quad*4 + r)*392 + nt*16 + nn] = bf1pack(h);
        }
    }
    __syncthreads();

    bhalf8 bf2[12];
    #pragma unroll
    for (int ks = 0; ks < 12; ++ks)
        bf2[ks] = *(const bhalf8*)&lh[(tt*16 + nn)*392 + ks*32 + quad*8];

    #pragma unroll 1
    for (int i = 0; i < 3; ++i) {
        int mt = hv_*3 + i;
        floatx4 acc = (floatx4){0.f,0.f,0.f,0.f};
        #pragma unroll
        for (int ks = 0; ks < 12; ++ks) {
            bhalf8 af = *(const bhalf8*)(w2P + ((size_t)(mt*12 + ks)*64 + lane)*8);
            acc = __builtin_amdgcn_mfma_f32_16x16x32_bf16(af, bf2[ks], acc, 0, 0, 0);
        }
        #pragma unroll
        for (int r = 0; r < 4; ++r) {
            int c = mt*16 + quad*4 + r;
            size_t addr = ((size_t)n*CC_ + c)*HWHW + hw0 + tt*16 + nn;
            out[addr] = vt[c*34 + tt*16 + nn] + (acc[r] + b2[c]);
        }
    }
}

// ---------------------------------------------------------------------------
extern "C" void kernel_launch(void* const* d_in, const int* in_sizes, int n_in,
                              void* d_out, int out_size, void* d_ws, size_t ws_size,
                              hipStream_t stream) {
    const float* x    = (const float*)d_in[0];
    const float* ln1w = (const float*)d_in[1];
    const float* ln1b = (const float*)d_in[2];
    const float* wnn  = (const float*)d_in[3];
    const float* ln2w = (const float*)d_in[4];
    const float* ln2b = (const float*)d_in[5];
    const float* w1   = (const float*)d_in[6];
    const float* b1   = (const float*)d_in[7];
    const float* w2   = (const float*)d_in[8];
    const float* b2   = (const float*)d_in[9];
    float* out = (float*)d_out;
    char* ws = (char*)d_ws;

    ushort_t* WfP  = (ushort_t*)ws;                   ws += 73728*2;
    ushort_t* WtP  = (ushort_t*)ws;                   ws += 73728*2;
    ushort_t* w1P  = (ushort_t*)ws;                   ws += 36864*2;
    ushort_t* w2P  = (ushort_t*)ws;                   ws += 36864*2;
    unsigned* Xp   = (unsigned*)ws;                   ws += (size_t)(NELEM/2)*4;
    unsigned* Hu0  = (unsigned*)ws;                   ws += (size_t)(NELEM/2)*4;
    unsigned* Hu1  = (unsigned*)ws;                   ws += (size_t)(NELEM/2)*4;
    float*    SA   = (float*)ws;                      ws += (size_t)4*NPIX*4;
    float*    SB   = (float*)ws;                      ws += (size_t)4*NPIX*4;

    // bf16(1/96) on host (RNE), and the matching per-group channel-sum init
    union { float f; unsigned u; } cv; cv.f = 1.f/96.f;
    unsigned ur = cv.u + 0x7fffu + ((cv.u >> 16) & 1u);
    unsigned short hbits = (unsigned short)(ur >> 16);
    unsigned huInit = ((unsigned)hbits << 16) | hbits;
    union { float f; unsigned u; } hv; hv.u = ((unsigned)hbits) << 16;
    float sInit = 24.f * hv.f;

    // One fused prep launch: wnorm+wpack, mlppack, ln1.
    prep_kernel<<<236, 256, 0, stream>>>(wnn, WfP, WtP, w1, w2, w1P, w2P,
                                         x, ln1w, ln1b, Xp);
    // it0 staging is constant-generated in-kernel: no Hu0/SA fills needed.

    for (int it = 0; it < NITER; ++it) {
        const unsigned* HuI  = (it & 1) ? Hu1 : Hu0;
        unsigned*       HuO  = (it & 1) ? Hu0 : Hu1;
        const float*    Scur = (it & 1) ? SB : SA;
        float*          Snxt = (it & 1) ? SA : SB;
        nnmf_mfma_kernel<<<512, 512, 0, stream>>>(HuI, HuO, Scur, Snxt, WtP, WfP, Xp,
                                                  (it == 0) ? 1 : 0, huInit, sInit);
    }
    // 25 iterations: final Hu in Hu1, final S in SB

    mlpres_kernel<<<NPIX/32, 256, 0, stream>>>(x, Hu1, SB, ln2w, ln2b,
                                               w1P, b1, w2P, b2, out);
}

// Round 18
// 386.960 us; speedup vs baseline: 1.0115x; 1.0115x over previous
//
#include <hip/hip_runtime.h>
#include <math.h>
#include <string.h>

typedef unsigned short ushort_t;
typedef __attribute__((ext_vector_type(8))) short bhalf8;
typedef __attribute__((ext_vector_type(4))) float floatx4;

// Problem constants
#define NN    8
#define CC_   96
#define HH    56
#define WW    56
#define HWHW  (HH*WW)            // 3136
#define NPIX  (NN*HWHW)          // 25088
#define NELEM (NN*CC_*HWHW)      // 2408448
#define GROUPS 4
#define IG    24                 // channels per group
#define NITER 25
#define EPSV  1e-12f
#define TS    40                 // LDS ch-slot stride (ushorts) = 80 B

// bf16 helpers (RNE)
__device__ __forceinline__ unsigned bf2pack(float a, float b) {
    unsigned ua = __float_as_uint(a), ub = __float_as_uint(b);
    ua += 0x7fffu + ((ua >> 16) & 1u);
    ub += 0x7fffu + ((ub >> 16) & 1u);
    return (ua >> 16) | (ub & 0xffff0000u);
}
__device__ __forceinline__ ushort_t bf1pack(float a) {
    unsigned ua = __float_as_uint(a);
    ua += 0x7fffu + ((ua >> 16) & 1u);
    return (ushort_t)(ua >> 16);
}
__device__ __forceinline__ float bflo(unsigned u) { return __uint_as_float(u << 16); }
__device__ __forceinline__ float bfhi(unsigned u) { return __uint_as_float(u & 0xffff0000u); }

// fast reciprocal: v_rcp_f32 (~1 ulp), error far below bf16 pack rounding
__device__ __forceinline__ float rcpf(float x) {
    float r;
    asm("v_rcp_f32 %0, %1" : "=v"(r) : "v"(x));
    return r;
}

// Linear LDS addressing (R10): TS=40 ushorts = 20 dwords is bank-optimal for
// ds_read_b128 (8 consecutive lanes -> 8 disjoint 4-bank groups; nn/nn+8
// alias exactly = free 2-way).
__device__ __forceinline__ int swz(int slot, int u) {
    return slot*TS + u;
}

// ---------------------------------------------------------------------------
// Fused prep: blocks 0-3    = wnorm+wpack (per group g)
//             blocks 4-39   = mlppack (4 frag-sets per block)
//             blocks 40-235 = ln1 (128 px per block, 2 threads/px)
// Xp packed as uint2 channel-quads: Xp2[(ng*6+pr2)*HWHW + hw].
__global__ __launch_bounds__(256) void prep_kernel(
        const float* __restrict__ w_in,
        ushort_t* __restrict__ WfP, ushort_t* __restrict__ WtP,
        const float* __restrict__ w1, const float* __restrict__ w2,
        ushort_t* __restrict__ w1P, ushort_t* __restrict__ w2P,
        const float* __restrict__ x, const float* __restrict__ lw1,
        const float* __restrict__ lb1, unsigned* __restrict__ Xp) {
    __shared__ float wn[24*216];         // 20736 B (reused by ln1 reductions)
    __shared__ float rsum[24];
    int b = blockIdx.x;
    int tid = threadIdx.x;

    if (b < 4) {
        int g = b;
        if (tid < 24) {
            const float* wr = w_in + (size_t)(g*24 + tid)*216;
            float s = 0.f;
            for (int j = 0; j < 216; ++j) s += fabsf(wr[j]);
            rsum[tid] = s;
        }
        __syncthreads();
        for (int i = tid; i < 24*216; i += 256) {
            int row = i / 216;
            wn[i] = fabsf(w_in[(size_t)g*24*216 + i]) * rcpf(rsum[row] + EPSV);
        }
        __syncthreads();
        int lg = tid >> 6;               // 0..3
        int lane = tid & 63;
        int quad = lane >> 4, nn15 = lane & 15;
        #pragma unroll 1
        for (int i = 0; i < 9; ++i) {
            int fr  = lg + 4*i;          // 0..35
            int sel = fr / 18;
            int rem = fr % 18;
            int ot  = rem & 1;
            int tap = rem >> 1;
            int m = ot*16 + nn15;
            ushort_t v[8];
            #pragma unroll
            for (int j = 0; j < 8; ++j) {
                int kc = quad*8 + j;
                float val = 0.f;
                if (m < IG && kc < IG) {
                    if (sel == 0) val = wn[m*216 + kc*9 + tap];
                    else          val = wn[kc*216 + m*9 + (8 - tap)];
                }
                v[j] = bf1pack(val);
            }
            ushort_t* dst = (sel ? WtP : WfP) + ((size_t)((g*9 + tap)*2 + ot)*64 + lane)*8;
            *(uint4*)dst = *(uint4*)v;
        }
    } else if (b < 40) {
        int f = (b - 4)*4 + (tid >> 6);  // 0..143
        int lane = tid & 63;
        int quad = lane >> 4, nn15 = lane & 15;
        ushort_t v[8];
        if (f < 72) {
            int nt = f / 3, ks = f % 3;
            #pragma unroll
            for (int j = 0; j < 8; ++j)
                v[j] = bf1pack(w1[(size_t)(ks*32 + quad*8 + j)*384 + nt*16 + nn15]);
            *(uint4*)(w1P + ((size_t)f*64 + lane)*8) = *(uint4*)v;
        } else {
            int f2 = f - 72;
            int mt = f2 / 12, ks = f2 % 12;
            #pragma unroll
            for (int j = 0; j < 8; ++j)
                v[j] = bf1pack(w2[(size_t)(ks*32 + quad*8 + j)*96 + mt*16 + nn15]);
            *(uint4*)(w2P + ((size_t)f2*64 + lane)*8) = *(uint4*)v;
        }
    } else {
        // ---- LN1: 128 px/block, 2 threads per px (channel halves, reg cache)
        float* ps  = wn;                 // 256
        float* pss = wn + 256;           // 256
        float* psr = wn + 512;           // 256
        int pb = b - 40;                 // 0..195
        int px = tid & 127;
        int ch0 = (tid >> 7) * 48;       // 0 or 48
        int p = pb*128 + px;             // < NPIX exactly (196*128)
        int n = p / HWHW, hw = p % HWHW;
        const float* xp = x + (size_t)n*CC_*HWHW + (size_t)ch0*HWHW + hw;
        float v[48];
        float s = 0.f, ss = 0.f;
        #pragma unroll
        for (int j = 0; j < 48; ++j) {
            float vv = xp[(size_t)j*HWHW];
            v[j] = vv; s += vv; ss += vv*vv;
        }
        ps[tid] = s; pss[tid] = ss;
        __syncthreads();
        float S_  = ps[px]  + ps[128 + px];
        float SS_ = pss[px] + pss[128 + px];
        float u  = S_ * (1.f/CC_);
        float var = SS_ * (1.f/CC_) - u*u;
        float rs = rsqrtf(var + 1e-6f);
        float sr = 0.f;
        #pragma unroll
        for (int j = 0; j < 48; ++j) {
            float av = fmaxf((v[j]-u)*rs*lw1[ch0+j] + lb1[ch0+j], 0.f);
            v[j] = av; sr += av;
        }
        psr[tid] = sr;
        __syncthreads();
        float inv = 1.f / (psr[px] + psr[128 + px] + EPSV);
        #pragma unroll
        for (int q = 0; q < 12; ++q) {
            int c = ch0 + 4*q;
            uint2 pk;
            pk.x = bf2pack(v[4*q]*inv,   v[4*q+1]*inv);
            pk.y = bf2pack(v[4*q+2]*inv, v[4*q+3]*inv);
            int g = c / IG, pr2 = (c % IG) >> 2;
            *(uint2*)&Xp[2*(((size_t)(n*4+g)*6 + pr2)*HWHW + hw)] = pk;
        }
    }
}

// ---------------------------------------------------------------------------
// Fused NNMF iteration (MFMA), 7-row band, 512 blocks (uniform 2/CU).
// R9 vector layout (Hu/Xp uint2 quads, S float4) + R10 linear LDS addressing.
// R12 sacc epilogue; rt_ pad zeroing issued before the prefetch loop.
// R16 final (session best, 387.1 us): phase-B Xp loads in-phase (R17's
// pre-staging hoist regressed: VMEM queue saturation on the staging path).
__global__ __launch_bounds__(512, 4) void nnmf_mfma_kernel(
        const unsigned* __restrict__ HupI, unsigned* __restrict__ HupO,
        const float* __restrict__ Scur, float* __restrict__ Snxt,
        const ushort_t* __restrict__ WtP, const ushort_t* __restrict__ WfP,
        const unsigned* __restrict__ Xp,
        int it0, unsigned huInit, float sInit) {
    __shared__ ushort_t hn[352*TS];      // HuN tile [row11*32+pos][40]  28160 B
    __shared__ ushort_t rt_[288*TS];     // R   tile [row9*32+pos][40]   23040 B
    __shared__ float sacc[392];
    int b    = blockIdx.x;               // 512
    // XCD-aware decode: xcd = b&7, 4 ng-groups x 16 tiles per XCD
    int k_   = b >> 3;                   // 0..63
    int ng   = (b & 7)*4 + (k_ >> 4);    // 0..31
    int tile = k_ & 15;                  // 0..15
    int rtb  = tile >> 1;                // 0..7 (7-row bands)
    int half = tile & 1;
    int n    = ng >> 2;
    int g    = ng & 3;
    int tid  = threadIdx.x;
    int r0   = rtb*7;
    int xb   = half*28;
    unsigned plane6 = (unsigned)(n*4 + g)*6;

    int waveId = tid >> 6, lane = tid & 63;
    int quad = lane >> 4, nn = lane & 15;
    int otB = waveId & 1;
    int mbB = otB*16 + quad*4;           // phase-B output channel base

    // rt_ K-pad zeroing first: retired long before the barrier
    if (tid < 288) *(uint4*)&rt_[swz(tid, 24)] = (uint4){0u,0u,0u,0u};

    // convT weight frags early: latency overlaps staging (ot-split: 9 frags)
    bhalf8 afrB[9];
    {
        const ushort_t* ap = WtP + ((size_t)(g*9*2 + otB)*64 + lane)*8;
        #pragma unroll
        for (int t = 0; t < 9; ++t) afrB[t] = *(const bhalf8*)(ap + (size_t)t*2*64*8);
    }

    // ---- prefetch Hu (uint2) + S (float4) for staging; 11x32 grid, 6 pr2
    uint2 raw[6];
    float sSum[6];
    #pragma unroll
    for (int kk = 0; kk < 6; ++kk) {
        int idx = tid + kk*512;          // < 2816 guarded
        uint2 rv = {0u, 0u};
        float st = 0.f;
        if (idx < 2816) {
            int pr2  = idx / 352;        // 0..7 (6 used)
            int slot = idx - pr2*352;    // 0..351
            int r = slot >> 5, q = slot & 31;
            int gr = r0 - 2 + r, gc = xb - 2 + q;
            if (!it0 && pr2 < 6 && gr >= 0 && gr < HH && gc >= 0 && gc < WW) {
                unsigned off = (unsigned)(gr*WW + gc);
                unsigned pix = (unsigned)(n*HWHW) + off;
                rv = *(const uint2*)&HupI[2*((size_t)(plane6 + pr2)*HWHW + off)];
                float4 sv = *(const float4*)&Scur[4*(size_t)pix];
                st = sv.x + sv.y + sv.z + sv.w;
            }
        }
        raw[kk] = rv;
        sSum[kk] = st;
    }

    // ---- stage HuN = Hu/S (bf16); pr2 6,7 zero the K-pad chunks
    #pragma unroll
    for (int kk = 0; kk < 6; ++kk) {
        int idx = tid + kk*512;
        if (idx < 2816) {
            int pr2  = idx / 352;
            int slot = idx - pr2*352;
            int r = slot >> 5, q = slot & 31;
            int gr = r0 - 2 + r, gc = xb - 2 + q;
            uint2 pk = {0u, 0u};
            if (pr2 < 6 && gr >= 0 && gr < HH && gc >= 0 && gc < WW) {
                if (it0) {
                    float si = rcpf(4.f*sInit + EPSV);
                    float hval = bflo(huInit) * si;
                    pk.x = bf2pack(hval, hval);
                    pk.y = pk.x;
                } else {
                    float si = rcpf(sSum[kk] + EPSV);
                    pk.x = bf2pack(bflo(raw[kk].x)*si, bfhi(raw[kk].x)*si);
                    pk.y = bf2pack(bflo(raw[kk].y)*si, bfhi(raw[kk].y)*si);
                }
            }
            *(uint2*)&hn[swz(slot, 4*pr2)] = pk;
        }
    }
    __syncthreads();

    // ---- Phase B: convT -> R band (9 rows x 30 px) in LDS; 36 tasks
    {
        #pragma unroll
        for (int i = 0; i < 5; ++i) {
            int tk = waveId + 8*i;       // 0..39, valid < 36; tk&1 == otB
            if (tk < 36) {
                int pt  = (tk >> 1) & 1;
                int row = tk >> 2;       // 0..8 (gr = r0-1+row)
                int x0R = pt*14;
                // hoisted ratio operands (one uint2 = 4 channels)
                unsigned xa = 0u, xc = 0u;
                int gr = r0 - 1 + row, gc = xb - 1 + x0R + nn;
                if (mbB < IG && gr >= 0 && gr < HH && gc >= 0 && gc < WW) {
                    unsigned off = (unsigned)(gr*WW + gc);
                    uint2 xv = *(const uint2*)&Xp[2*((size_t)(plane6 + (mbB >> 2))*HWHW + off)];
                    xa = xv.x; xc = xv.y;
                }
                floatx4 acc = (floatx4){0.f,0.f,0.f,0.f};
                #pragma unroll
                for (int t = 0; t < 9; ++t) {
                    int ky = t / 3, kx = t % 3;
                    bhalf8 bfr = *(const bhalf8*)
                        &hn[swz((row + ky)*32 + kx + nn + x0R, quad*8)];
                    acc = __builtin_amdgcn_mfma_f32_16x16x32_bf16(afrB[t], bfr, acc, 0, 0, 0);
                }
                if (mbB < IG) {
                    int slot = row*32 + x0R + nn;
                    *(unsigned*)&rt_[swz(slot, mbB)] =
                        bf2pack(bflo(xa)*rcpf(acc[0]+EPSV), bfhi(xa)*rcpf(acc[1]+EPSV));
                    *(unsigned*)&rt_[swz(slot, mbB + 2)] =
                        bf2pack(bflo(xc)*rcpf(acc[2]+EPSV), bfhi(xc)*rcpf(acc[3]+EPSV));
                }
            }
        }
    }
    __syncthreads();

    // ---- Phase C: forward conv + mult. update; 28 tasks (7r x 2xt x 2ot)
    {
        const ushort_t* ap = WfP + ((size_t)(g*9*2 + otB)*64 + lane)*8;
        bhalf8 afr[9];
        #pragma unroll
        for (int t = 0; t < 9; ++t) afr[t] = *(const bhalf8*)(ap + (size_t)t*2*64*8);
        int mb = mbB;

        #pragma unroll
        for (int i = 0; i < 4; ++i) {
            int tc = waveId + 8*i;       // 0..31, valid < 28; tc&1 == otB
            if (tc < 28) {
                int xt = (tc >> 1) & 1;
                int w  = tc >> 2;        // out row in band, 0..6
                int px0 = xt*12;
                floatx4 acc = (floatx4){0.f,0.f,0.f,0.f};
                #pragma unroll
                for (int t = 0; t < 9; ++t) {
                    int ky = t / 3, kx = t % 3;
                    bhalf8 bfr = *(const bhalf8*)
                        &rt_[swz((w + ky)*32 + kx + nn + px0, quad*8)];
                    acc = __builtin_amdgcn_mfma_f32_16x16x32_bf16(afr[t], bfr, acc, 0, 0, 0);
                }

                int grow = r0 + w;
                int pxh = px0 + nn;      // 0..27
                float psum = 0.f;
                if (mb < IG) {
                    unsigned off = (unsigned)(grow*WW + xb + pxh);
                    uint2 hv = *(const uint2*)&hn[swz((w + 2)*32 + pxh + 2, mb)];
                    float h0 = bflo(hv.x) * acc[0];
                    float h1 = bfhi(hv.x) * acc[1];
                    float h2 = bflo(hv.y) * acc[2];
                    float h3 = bfhi(hv.y) * acc[3];
                    uint2 po; po.x = bf2pack(h0, h1); po.y = bf2pack(h2, h3);
                    *(uint2*)&HupO[2*((size_t)(plane6 + (mb >> 2))*HWHW + off)] = po;
                    psum = h0 + h1 + h2 + h3;
                }
                psum += __shfl_down(psum, 32, 64);
                psum += __shfl_down(psum, 16, 64);
                if (lane < 16) sacc[otB*196 + w*28 + pxh] = psum;
            }
        }
    }
    __syncthreads();
    if (tid < 196) {
        unsigned pix = (unsigned)(n*HWHW + (r0 + tid/28)*WW + xb + (tid % 28));
        Snxt[4*(size_t)pix + g] = sacc[tid] + sacc[196 + tid];
    }
}

// ---------------------------------------------------------------------------
// Fused residual + LN2 + MLP: 32 tokens/block, 256 thr (R10, verified).
__global__ __launch_bounds__(256) void mlpres_kernel(
        const float* __restrict__ x, const unsigned* __restrict__ Hup,
        const float* __restrict__ S4,
        const float* __restrict__ lw, const float* __restrict__ lb,
        const ushort_t* __restrict__ w1P, const float* __restrict__ b1,
        const ushort_t* __restrict__ w2P, const float* __restrict__ b2,
        float* __restrict__ out) {
    __shared__ ushort_t lh[32*392];      // 25088 B
    __shared__ unsigned xln[32*52];      // 6656 B
    __shared__ float vt[96*34];          // 13056 B
    __shared__ float redS[8*32], redSS[8*32];
    __shared__ float uArr[32], rsArr[32];
    int blk = blockIdx.x;                // 784
    int tid = threadIdx.x;
    int p0  = blk * 32;
    int n   = p0 / HWHW;                 // HWHW % 32 == 0: no straddle
    int hw0 = p0 % HWHW;

    // ---- LN phase: px = tid&31, cg = tid>>5 (12 channels each)
    {
        int px = tid & 31, cg = tid >> 5;
        int p  = p0 + px, hw = hw0 + px;
        float4 sv = *(const float4*)&S4[4*(size_t)p];
        float stot = sv.x + sv.y + sv.z + sv.w;
        float sinv = 1.f / (stot + EPSV);
        int g = cg >> 1;
        unsigned plane6 = (unsigned)(n*4 + g)*6 + (unsigned)((cg & 1)*3);
        size_t xbase = (size_t)n*CC_*HWHW + hw;
        float v[12];
        float s = 0.f, ss = 0.f;
        #pragma unroll
        for (int j2 = 0; j2 < 3; ++j2) {
            int c = cg*12 + 4*j2;
            uint2 hu = *(const uint2*)&Hup[2*((size_t)(plane6 + j2)*HWHW + hw)];
            float h[4] = { bflo(hu.x), bfhi(hu.x), bflo(hu.y), bfhi(hu.y) };
            #pragma unroll
            for (int j = 0; j < 4; ++j) {
                float vv = x[xbase + (size_t)(c+j)*HWHW] + h[j] * sinv;
                v[4*j2 + j] = vv;
                s += vv; ss += vv*vv;
            }
        }
        redS[cg*32 + px] = s; redSS[cg*32 + px] = ss;
        __syncthreads();
        if (tid < 32) {
            float S_ = 0.f, SS_ = 0.f;
            #pragma unroll
            for (int k = 0; k < 8; ++k) { S_ += redS[k*32 + tid]; SS_ += redSS[k*32 + tid]; }
            float u  = S_ * (1.f/CC_);
            float var = SS_ * (1.f/CC_) - u*u;
            uArr[tid] = u; rsArr[tid] = rsqrtf(var + 1e-5f);
        }
        __syncthreads();
        float u = uArr[px], rs = rsArr[px];
        #pragma unroll
        for (int j = 0; j < 6; ++j) {
            int c = cg*12 + 2*j;
            float a0 = (v[2*j]   - u)*rs*lw[c]   + lb[c];
            float a1 = (v[2*j+1] - u)*rs*lw[c+1] + lb[c+1];
            xln[px*52 + cg*6 + j] = bf2pack(a0, a1);
            vt[c*34 + px]     = v[2*j];
            vt[(c+1)*34 + px] = v[2*j+1];
        }
    }
    __syncthreads();

    // ---- MLP phase: 4 waves; tt = token-tile (0/1), hv_ = nt/mt half
    int wv  = tid >> 6, lane = tid & 63;
    int quad = lane >> 4, nn = lane & 15;
    int tt  = wv >> 1;
    int hv_ = wv & 1;

    bhalf8 a1[3];
    #pragma unroll
    for (int ks = 0; ks < 3; ++ks)
        a1[ks] = *(const bhalf8*)&xln[(tt*16 + nn)*52 + ks*16 + quad*4];

    #pragma unroll 1
    for (int i = 0; i < 12; ++i) {
        int nt = hv_*12 + i;
        floatx4 acc = (floatx4){0.f,0.f,0.f,0.f};
        #pragma unroll
        for (int ks = 0; ks < 3; ++ks) {
            bhalf8 bfr = *(const bhalf8*)(w1P + ((size_t)(nt*3 + ks)*64 + lane)*8);
            acc = __builtin_amdgcn_mfma_f32_16x16x32_bf16(a1[ks], bfr, acc, 0, 0, 0);
        }
        float b1v = b1[nt*16 + nn];
        #pragma unroll
        for (int r = 0; r < 4; ++r) {
            float h = acc[r] + b1v;
            h = 0.5f * h * (1.f + erff(h * 0.70710678118654752440f));
            lh[(tt*16 + quad*4 + r)*392 + nt*16 + nn] = bf1pack(h);
        }
    }
    __syncthreads();

    bhalf8 bf2[12];
    #pragma unroll
    for (int ks = 0; ks < 12; ++ks)
        bf2[ks] = *(const bhalf8*)&lh[(tt*16 + nn)*392 + ks*32 + quad*8];

    #pragma unroll 1
    for (int i = 0; i < 3; ++i) {
        int mt = hv_*3 + i;
        floatx4 acc = (floatx4){0.f,0.f,0.f,0.f};
        #pragma unroll
        for (int ks = 0; ks < 12; ++ks) {
            bhalf8 af = *(const bhalf8*)(w2P + ((size_t)(mt*12 + ks)*64 + lane)*8);
            acc = __builtin_amdgcn_mfma_f32_16x16x32_bf16(af, bf2[ks], acc, 0, 0, 0);
        }
        #pragma unroll
        for (int r = 0; r < 4; ++r) {
            int c = mt*16 + quad*4 + r;
            size_t addr = ((size_t)n*CC_ + c)*HWHW + hw0 + tt*16 + nn;
            out[addr] = vt[c*34 + tt*16 + nn] + (acc[r] + b2[c]);
        }
    }
}

// ---------------------------------------------------------------------------
extern "C" void kernel_launch(void* const* d_in, const int* in_sizes, int n_in,
                              void* d_out, int out_size, void* d_ws, size_t ws_size,
                              hipStream_t stream) {
    const float* x    = (const float*)d_in[0];
    const float* ln1w = (const float*)d_in[1];
    const float* ln1b = (const float*)d_in[2];
    const float* wnn  = (const float*)d_in[3];
    const float* ln2w = (const float*)d_in[4];
    const float* ln2b = (const float*)d_in[5];
    const float* w1   = (const float*)d_in[6];
    const float* b1   = (const float*)d_in[7];
    const float* w2   = (const float*)d_in[8];
    const float* b2   = (const float*)d_in[9];
    float* out = (float*)d_out;
    char* ws = (char*)d_ws;

    ushort_t* WfP  = (ushort_t*)ws;                   ws += 73728*2;
    ushort_t* WtP  = (ushort_t*)ws;                   ws += 73728*2;
    ushort_t* w1P  = (ushort_t*)ws;                   ws += 36864*2;
    ushort_t* w2P  = (ushort_t*)ws;                   ws += 36864*2;
    unsigned* Xp   = (unsigned*)ws;                   ws += (size_t)(NELEM/2)*4;
    unsigned* Hu0  = (unsigned*)ws;                   ws += (size_t)(NELEM/2)*4;
    unsigned* Hu1  = (unsigned*)ws;                   ws += (size_t)(NELEM/2)*4;
    float*    SA   = (float*)ws;                      ws += (size_t)4*NPIX*4;
    float*    SB   = (float*)ws;                      ws += (size_t)4*NPIX*4;

    // bf16(1/96) on host (RNE), and the matching per-group channel-sum init
    union { float f; unsigned u; } cv; cv.f = 1.f/96.f;
    unsigned ur = cv.u + 0x7fffu + ((cv.u >> 16) & 1u);
    unsigned short hbits = (unsigned short)(ur >> 16);
    unsigned huInit = ((unsigned)hbits << 16) | hbits;
    union { float f; unsigned u; } hv; hv.u = ((unsigned)hbits) << 16;
    float sInit = 24.f * hv.f;

    // One fused prep launch: wnorm+wpack, mlppack, ln1.
    prep_kernel<<<236, 256, 0, stream>>>(wnn, WfP, WtP, w1, w2, w1P, w2P,
                                         x, ln1w, ln1b, Xp);
    // it0 staging is constant-generated in-kernel: no Hu0/SA fills needed.

    for (int it = 0; it < NITER; ++it) {
        const unsigned* HuI  = (it & 1) ? Hu1 : Hu0;
        unsigned*       HuO  = (it & 1) ? Hu0 : Hu1;
        const float*    Scur = (it & 1) ? SB : SA;
        float*          Snxt = (it & 1) ? SA : SB;
        nnmf_mfma_kernel<<<512, 512, 0, stream>>>(HuI, HuO, Scur, Snxt, WtP, WfP, Xp,
                                                  (it == 0) ? 1 : 0, huInit, sInit);
    }
    // 25 iterations: final Hu in Hu1, final S in SB

    mlpres_kernel<<<NPIX/32, 256, 0, stream>>>(x, Hu1, SB, ln2w, ln2b,
                                               w1P, b1, w2P, b2, out);
}